// Round 12
// baseline (331.041 us; speedup 1.0000x reference)
//
#include <hip/hip_runtime.h>
#include <hip/hip_bf16.h>

typedef unsigned short u16;
typedef __attribute__((ext_vector_type(8))) short s16x8;
typedef __attribute__((ext_vector_type(4))) float f32x4;
typedef __attribute__((ext_vector_type(16))) float f32x16;
typedef __attribute__((ext_vector_type(4))) float f32x4v;
typedef __attribute__((ext_vector_type(4))) u16 u16x4;

#define DIM 2048
#define NH 32
#define NKV 8
#define HD 64
#define TT 2048
#define BB 2
#define MT (BB * TT)

__device__ __forceinline__ u16 f2bf(float f) {
    union { float f; unsigned u; } v; v.f = f;
    unsigned r = v.u + 0x7FFFu + ((v.u >> 16) & 1u);
    return (u16)(r >> 16);
}
__device__ __forceinline__ float bf2f(u16 h) {
    union { unsigned u; float f; } v; v.u = ((unsigned)h) << 16;
    return v.f;
}
__device__ __forceinline__ u16 cvtbf(float f) {
    __hip_bfloat16 hb = __float2bfloat16(f);
    return *reinterpret_cast<u16*>(&hb);
}
__device__ __forceinline__ void plane32swap(unsigned& a, unsigned& b) {
#if defined(__has_builtin)
#if __has_builtin(__builtin_amdgcn_permlane32_swap)
    auto t = __builtin_amdgcn_permlane32_swap((int)a, (int)b, false, false);
    a = (unsigned)t[0]; b = (unsigned)t[1];
#else
    asm volatile("v_permlane32_swap_b32 %0, %1" : "+v"(a), "+v"(b));
#endif
#else
    asm volatile("v_permlane32_swap_b32 %0, %1" : "+v"(a), "+v"(b));
#endif
}

// ---------------- fused f32 -> bf16 conversion for all 5 tensors ----------------
__global__ void k_convert_all(const float* __restrict__ x, const float* __restrict__ wq,
                              const float* __restrict__ wk, const float* __restrict__ wv,
                              const float* __restrict__ wo,
                              u16* __restrict__ xb, u16* __restrict__ wqkv, u16* __restrict__ wob) {
    long i = (long)(blockIdx.x * 256 + threadIdx.x) * 4;
    const float* src; u16* dst; long o = i;
    if (o < 8388608L)            { src = x;  dst = xb; }
    else if ((o -= 8388608L) < 4194304L) { src = wq; dst = wqkv; }
    else if ((o -= 4194304L) < 1048576L) { src = wk; dst = wqkv + 4194304L; }
    else if ((o -= 1048576L) < 1048576L) { src = wv; dst = wqkv + 5242880L; }
    else { o -= 1048576L;          src = wo; dst = wob; }
    f32x4v f = *(const f32x4v*)(src + o);
    u16x4 out;
    #pragma unroll
    for (int e = 0; e < 4; ++e) out[e] = f2bf(f[e]);
    *(u16x4*)(dst + o) = out;
}

// ---------------- 256 x (64*BNF) 8-phase bf16 GEMM: C = A @ B^T ----------------
template<int BNF, bool OUTF32>
__global__ __launch_bounds__(512, 2) void k_gemm256(const u16* __restrict__ A, const u16* __restrict__ B,
                                                    void* __restrict__ C, int M, int N, int K) {
    constexpr int BN = 64 * BNF;
    constexpr int BH = 2048 * BNF;               // B half-tile size in u16
    __shared__ u16 LDS[32768 + 4 * BH];
    const int nTn = N / BN;
    const int nwg = gridDim.x;
    const int wg = (blockIdx.x & 7) * (nwg >> 3) + (blockIdx.x >> 3);
    const int tm = wg / nTn, tn = wg % nTn;
    const int tid = threadIdx.x, wid = tid >> 6, lane = tid & 63;
    const int wr = wid >> 2, wc = wid & 3;
    const u16* Ab = A + (size_t)tm * 256 * K;
    const u16* Bb = B + (size_t)tn * BN * K;

    f32x4 acc[8][BNF] = {};
    s16x8 af[4], bfr[BNF];

    auto STAGE_A = [&](int buf, int kk, int kt) {
        u16* base = LDS + (buf * 2 + kk) * 8192;
        const u16* g = Ab + kt * 64 + kk * 32;
        #pragma unroll
        for (int i = 0; i < 2; ++i) {
            const int s = i * 512 + tid;
            const int row = s >> 2;
            const int cl = (s & 3) ^ ((row >> 1) & 3);
            __builtin_amdgcn_global_load_lds(
                (const __attribute__((address_space(1))) void*)(g + (size_t)row * K + cl * 8),
                (__attribute__((address_space(3))) void*)(base + (i * 512 + wid * 64) * 8), 16, 0, 0);
        }
    };
    auto STAGE_B = [&](int buf, int kk, int kt) {
        u16* base = LDS + 32768 + (buf * 2 + kk) * BH;
        const u16* g = Bb + kt * 64 + kk * 32;
        auto one = [&](int ch) {
            const int row = ch * 16 + (lane >> 2);
            const int cl = (lane & 3) ^ ((row >> 1) & 3);
            __builtin_amdgcn_global_load_lds(
                (const __attribute__((address_space(1))) void*)(g + (size_t)row * K + cl * 8),
                (__attribute__((address_space(3))) void*)(base + ch * 512), 16, 0, 0);
        };
        if constexpr (BNF == 4) { one(wid); one(8 + wid); }
        else if constexpr (BNF == 3) { one(wid); one(8 + (wid & 3)); }   // waves 4-7 duplicate
        else { one(wid); }
    };
    auto LDA = [&](int buf, int kk, int mh) {
        const u16* base = LDS + (buf * 2 + kk) * 8192;
        #pragma unroll
        for (int m2 = 0; m2 < 4; ++m2) {
            const int row = wr * 128 + (mh * 4 + m2) * 16 + (lane & 15);
            const int cl = (lane >> 4) ^ ((row >> 1) & 3);
            af[m2] = *(const s16x8*)(base + row * 32 + cl * 8);
        }
    };
    auto LDB = [&](int buf, int kk) {
        const u16* base = LDS + 32768 + (buf * 2 + kk) * BH;
        #pragma unroll
        for (int n = 0; n < BNF; ++n) {
            const int row = wc * (16 * BNF) + n * 16 + (lane & 15);
            const int cl = (lane >> 4) ^ ((row >> 1) & 3);
            bfr[n] = *(const s16x8*)(base + row * 32 + cl * 8);
        }
    };
    auto MFMA16 = [&](int mh) {
        asm volatile("s_waitcnt lgkmcnt(0)" ::: "memory");
        __builtin_amdgcn_sched_barrier(0);
        __builtin_amdgcn_s_setprio(1);
        #pragma unroll
        for (int m2 = 0; m2 < 4; ++m2)
            #pragma unroll
            for (int n = 0; n < BNF; ++n)
                acc[mh * 4 + m2][n] =
                    __builtin_amdgcn_mfma_f32_16x16x32_bf16(af[m2], bfr[n], acc[mh * 4 + m2][n], 0, 0, 0);
        __builtin_amdgcn_s_setprio(0);
    };

    #define VMID() do { if constexpr (BNF == 2) asm volatile("s_waitcnt vmcnt(6)" ::: "memory"); \
                        else                    asm volatile("s_waitcnt vmcnt(8)" ::: "memory"); } while (0)
    #define VONE() do { if constexpr (BNF == 2) asm volatile("s_waitcnt vmcnt(3)" ::: "memory"); \
                        else                    asm volatile("s_waitcnt vmcnt(4)" ::: "memory"); } while (0)

    STAGE_A(0, 0, 0); STAGE_B(0, 0, 0);
    STAGE_A(0, 1, 0); STAGE_B(0, 1, 0);
    STAGE_A(1, 0, 1); STAGE_B(1, 0, 1);
    VMID();
    __builtin_amdgcn_s_barrier();

    const int NI = K >> 7;
    for (int it = 0; it < NI; ++it) {
        const bool last = (it == NI - 1);
        const int t1 = 2 * it + 1;
        LDA(0, 0, 0); LDB(0, 0);
        STAGE_A(1, 1, t1);
        __builtin_amdgcn_s_barrier();
        MFMA16(0);
        __builtin_amdgcn_s_barrier();

        LDA(0, 0, 1);
        STAGE_B(1, 1, t1);
        __builtin_amdgcn_s_barrier();
        MFMA16(1);
        VMID();
        __builtin_amdgcn_s_barrier();

        LDA(0, 1, 0); LDB(0, 1);
        if (!last) STAGE_A(0, 0, t1 + 1);
        __builtin_amdgcn_s_barrier();
        MFMA16(0);
        __builtin_amdgcn_s_barrier();

        LDA(0, 1, 1);
        if (!last) STAGE_B(0, 0, t1 + 1);
        __builtin_amdgcn_s_barrier();
        MFMA16(1);
        if (!last) VMID(); else VONE();
        __builtin_amdgcn_s_barrier();

        LDA(1, 0, 0); LDB(1, 0);
        if (!last) STAGE_A(0, 1, t1 + 1);
        __builtin_amdgcn_s_barrier();
        MFMA16(0);
        __builtin_amdgcn_s_barrier();

        LDA(1, 0, 1);
        if (!last) STAGE_B(0, 1, t1 + 1);
        __builtin_amdgcn_s_barrier();
        MFMA16(1);
        if (!last) VMID(); else asm volatile("s_waitcnt vmcnt(0)" ::: "memory");
        __builtin_amdgcn_s_barrier();

        LDA(1, 1, 0); LDB(1, 1);
        if (!last) STAGE_A(1, 0, t1 + 2);
        __builtin_amdgcn_s_barrier();
        MFMA16(0);
        __builtin_amdgcn_s_barrier();

        LDA(1, 1, 1);
        if (!last) STAGE_B(1, 0, t1 + 2);
        __builtin_amdgcn_s_barrier();
        MFMA16(1);
        if (!last) VMID();
        __builtin_amdgcn_s_barrier();
    }
    #undef VMID
    #undef VONE

    #pragma unroll
    for (int mf = 0; mf < 8; ++mf)
        #pragma unroll
        for (int n = 0; n < BNF; ++n)
            #pragma unroll
            for (int r = 0; r < 4; ++r) {
                const int row = tm * 256 + wr * 128 + mf * 16 + (lane >> 4) * 4 + r;
                const int col = tn * BN + wc * (16 * BNF) + n * 16 + (lane & 15);
                if (OUTF32) ((float*)C)[(size_t)row * N + col] = acc[mf][n][r];
                else        ((u16*)C)[(size_t)row * N + col] = f2bf(acc[mf][n][r]);
            }
}

// ---------------- RoPE + scatter, vectorized; q pre-scaled by (1/8)*log2(e) ----------------
__global__ void k_rope(const u16* __restrict__ qkv, const float* __restrict__ ct, const float* __restrict__ st,
                       u16* __restrict__ qo, u16* __restrict__ ko, u16* __restrict__ vo) {
    const int idx = blockIdx.x * 256 + threadIdx.x;
    const int c = idx % 384;
    const int bt = idx / 384;
    const int b = bt / TT, t = bt % TT;
    const s16x8 v = *(const s16x8*)(qkv + (size_t)bt * 3072 + c * 8);
    if (c < 320) {
        const bool isq = c < 256;
        const int base = isq ? c : c - 256;
        const int hh = base >> 3;
        const int di0 = (base & 7) * 4;
        const f32x4v cc = *(const f32x4v*)(ct + t * 32 + di0);
        const f32x4v ss = *(const f32x4v*)(st + t * 32 + di0);
        const float QS = isq ? 0.18033688f : 1.0f;
        s16x8 o;
        #pragma unroll
        for (int p = 0; p < 4; ++p) {
            const float x0 = bf2f((u16)v[2 * p]), x1 = bf2f((u16)v[2 * p + 1]);
            o[2 * p]     = (short)cvtbf((x0 * cc[p] - x1 * ss[p]) * QS);
            o[2 * p + 1] = (short)cvtbf((x0 * ss[p] + x1 * cc[p]) * QS);
        }
        u16* dst = isq ? (qo + ((size_t)(b * NH + hh) * TT + t) * HD + 2 * di0)
                       : (ko + ((size_t)(b * NKV + hh) * TT + t) * HD + 2 * di0);
        *(s16x8*)dst = o;
    } else {
        const int base = c - 320;
        const int hh = base >> 3;
        const int d0 = (base & 7) * 8;
        *(s16x8*)(vo + ((size_t)(b * NKV + hh) * TT + t) * HD + d0) = v;
    }
}

// ---------------- V transpose: vp [bg][t][d] -> vt [bg][d][t] ----------------
__global__ __launch_bounds__(256) void k_vtrans(const u16* __restrict__ vp, u16* __restrict__ vt) {
    __shared__ u16 tile[64][66];
    const int bg = blockIdx.x >> 5;
    const int t0 = (blockIdx.x & 31) * 64;
    const int tid = threadIdx.x;
    #pragma unroll
    for (int c = 0; c < 2; ++c) {
        const int idx = c * 256 + tid;
        const int tl = idx >> 3, dc = idx & 7;
        s16x8 v = *(const s16x8*)(vp + ((size_t)bg * TT + t0 + tl) * HD + dc * 8);
        *(s16x8*)(&tile[tl][dc * 8]) = v;
    }
    __syncthreads();
    #pragma unroll
    for (int c = 0; c < 2; ++c) {
        const int idx = c * 256 + tid;
        const int d = idx >> 3, tc = idx & 7;
        s16x8 v;
        #pragma unroll
        for (int e = 0; e < 8; ++e) v[e] = (short)tile[tc * 8 + e][d];
        *(s16x8*)(vt + ((size_t)bg * HD + d) * TT + t0 + tc * 8) = v;
    }
}

// ---------------- 8-wave QBLK=256 attention, intra-wave software pipeline ----------------
// Per iteration: vmcnt(0) -> barrier -> stage(j+2) -> QK(j+1)->s_out [MFMA first] ->
// softmax(s_in) [VALU overlaps matrix pipe] -> PV(j). Two statically-named S-sets (sA/sB),
// loop unrolled by 2 (ntiles always even). 3-buf LDS required: read Ks[(j+1)%3], Vs[j%3],
// write buf[(j+2)%3]. __launch_bounds__(512,4) caps VGPR at 128 so 2 blocks/CU fit.
__global__ __launch_bounds__(512, 4) void k_attn(const u16* __restrict__ Q, const u16* __restrict__ K,
                                                 const u16* __restrict__ Vtg, u16* __restrict__ O) {
    const int bid = blockIdx.x;                 // 512 = 8 qgroups x 64 bh
    const int gq = bid >> 6;
    const int qt8 = (gq < 4) ? (7 - gq) : (gq - 4);   // big first, pair-balanced
    const int bh = bid & 63;
    const int h = bh & 31;
    const int b = bh >> 5;
    const int g = h >> 2;
    __shared__ u16 Ks[3][4096];
    __shared__ u16 Vs[3][4096];                 // V^T tile: [d][kv]
    const int tid = threadIdx.x, wave = tid >> 6, lane = tid & 63;
    const int c = lane & 31, hi = lane >> 5;
    const u16* Qg = Q + ((size_t)(b * NH + h) * TT + qt8 * 256) * HD;
    const u16* Kg = K + (size_t)(b * NKV + g) * TT * HD;
    const u16* Vg = Vtg + (size_t)(b * NKV + g) * HD * TT;

    s16x8 qa[4];
    #pragma unroll
    for (int kb = 0; kb < 4; ++kb)
        qa[kb] = *(const s16x8*)(Qg + (size_t)(wave * 32 + c) * HD + kb * 16 + hi * 8);

    const int rl = lane >> 3, ccl = lane & 7;
    const int sc = ccl ^ rl;                    // chunk-XOR swizzle on source
    auto stage = [&](int jj, int bi) {
        const int r = wave * 8 + rl;            // wave covers rows [wave*8, wave*8+8)
        __builtin_amdgcn_global_load_lds(
            (const __attribute__((address_space(1))) void*)(Kg + ((size_t)(jj * 64 + r)) * HD + sc * 8),
            (__attribute__((address_space(3))) void*)(Ks[bi] + wave * 512), 16, 0, 0);
        __builtin_amdgcn_global_load_lds(
            (const __attribute__((address_space(1))) void*)(Vg + (size_t)r * TT + jj * 64 + sc * 8),
            (__attribute__((address_space(3))) void*)(Vs[bi] + wave * 512), 16, 0, 0);
    };

    f32x16 acc0 = {}, acc1 = {};
    float l = 0.f;
    const int ntiles = 4 * qt8 + 4;             // always even (multiple of 4)
    const int q_loc = wave * 32 + c;

    // one pipeline step: consumes S(j) in (i0,i1), produces S(j+1) into (o0,o1)
    auto body = [&](int j, f32x16& i0, f32x16& i1, f32x16& o0, f32x16& o1) {
        asm volatile("s_waitcnt vmcnt(0)" ::: "memory");   // tile j+1 landed (my 2 loads)
        __builtin_amdgcn_s_barrier();                      // publish j+1; all waves past reads of (j+2)%3
        if (j + 2 < ntiles) stage(j + 2, (j + 2) % 3);

        // QK(j+1) first: MFMA burst fills matrix pipe
        o0 = f32x16{}; o1 = f32x16{};
        if (j + 1 < ntiles) {
            const u16* Kb = Ks[(j + 1) % 3];
            __builtin_amdgcn_s_setprio(1);
            #pragma unroll
            for (int kb = 0; kb < 4; ++kb) {
                const s16x8 kf0 = *(const s16x8*)(Kb + c * 64 + (((2 * kb + hi) ^ ccl) * 8));
                const s16x8 kf1 = *(const s16x8*)(Kb + (32 + c) * 64 + (((2 * kb + hi) ^ ccl) * 8));
                o0 = __builtin_amdgcn_mfma_f32_32x32x16_bf16(kf0, qa[kb], o0, 0, 0, 0);
                o1 = __builtin_amdgcn_mfma_f32_32x32x16_bf16(kf1, qa[kb], o1, 0, 0, 0);
            }
            __builtin_amdgcn_s_setprio(0);
        }

        // softmax(tile j) on (i0,i1): VALU overlaps the matrix pipe
        if (j >= ntiles - 4) {                  // diagonal 256x256 region
            const int kb64 = (j - (ntiles - 4)) * 64;
            if (kb64 + 63 > wave * 32) {
                #pragma unroll
                for (int r = 0; r < 16; ++r) {
                    const int crow = (r & 3) + 8 * (r >> 2) + 4 * hi;
                    if (kb64 + crow > q_loc)      i0[r] = -1e30f;
                    if (kb64 + 32 + crow > q_loc) i1[r] = -1e30f;
                }
            }
        }
        #pragma unroll
        for (int r = 0; r < 16; ++r) {
            i0[r] = __builtin_amdgcn_exp2f(i0[r]); l += i0[r];
            i1[r] = __builtin_amdgcn_exp2f(i1[r]); l += i1[r];
        }
        unsigned W0[8], W1[8];
        #pragma unroll
        for (int m = 0; m < 8; ++m) {
            float a0f = i0[2 * m], a1f = i0[2 * m + 1];
            float b0f = i1[2 * m], b1f = i1[2 * m + 1];
            asm("v_cvt_pk_bf16_f32 %0, %1, %2" : "=v"(W0[m]) : "v"(a0f), "v"(a1f));
            asm("v_cvt_pk_bf16_f32 %0, %1, %2" : "=v"(W1[m]) : "v"(b0f), "v"(b1f));
        }
        s16x8 pa[4];
        #pragma unroll
        for (int ks = 0; ks < 4; ++ks) {
            const int base = 4 * (ks & 1);
            unsigned a0 = (ks < 2) ? W0[base + 0] : W1[base + 0];
            unsigned b0 = (ks < 2) ? W0[base + 2] : W1[base + 2];
            unsigned a1 = (ks < 2) ? W0[base + 1] : W1[base + 1];
            unsigned b1 = (ks < 2) ? W0[base + 3] : W1[base + 3];
            plane32swap(a0, b0);
            plane32swap(a1, b1);
            union { unsigned w[4]; s16x8 v; } u;
            u.w[0] = a0; u.w[1] = a1; u.w[2] = b0; u.w[3] = b1;
            pa[ks] = u.v;
        }

        // PV(j)
        const u16* Vb = Vs[j % 3];
        __builtin_amdgcn_s_setprio(1);
        #pragma unroll
        for (int kb = 0; kb < 4; ++kb) {
            const s16x8 vb0 = *(const s16x8*)(Vb + c * 64 + (((2 * kb + hi) ^ ccl) * 8));
            const s16x8 vb1 = *(const s16x8*)(Vb + (32 + c) * 64 + (((2 * kb + hi) ^ ccl) * 8));
            acc0 = __builtin_amdgcn_mfma_f32_32x32x16_bf16(pa[kb], vb0, acc0, 0, 0, 0);
            acc1 = __builtin_amdgcn_mfma_f32_32x32x16_bf16(pa[kb], vb1, acc1, 0, 0, 0);
        }
        __builtin_amdgcn_s_setprio(0);
    };

    // prologue: stage 0,1; compute QK(0)
    stage(0, 0);
    stage(1, 1);
    f32x16 sA0, sA1, sB0, sB1;
    asm volatile("s_waitcnt vmcnt(2)" ::: "memory");       // tile 0 landed (tile 1 in flight)
    __builtin_amdgcn_s_barrier();
    sA0 = f32x16{}; sA1 = f32x16{};
    {
        const u16* Kb = Ks[0];
        __builtin_amdgcn_s_setprio(1);
        #pragma unroll
        for (int kb = 0; kb < 4; ++kb) {
            const s16x8 kf0 = *(const s16x8*)(Kb + c * 64 + (((2 * kb + hi) ^ ccl) * 8));
            const s16x8 kf1 = *(const s16x8*)(Kb + (32 + c) * 64 + (((2 * kb + hi) ^ ccl) * 8));
            sA0 = __builtin_amdgcn_mfma_f32_32x32x16_bf16(kf0, qa[kb], sA0, 0, 0, 0);
            sA1 = __builtin_amdgcn_mfma_f32_32x32x16_bf16(kf1, qa[kb], sA1, 0, 0, 0);
        }
        __builtin_amdgcn_s_setprio(0);
    }

    for (int j = 0; j < ntiles; j += 2) {
        body(j,     sA0, sA1, sB0, sB1);
        body(j + 1, sB0, sB1, sA0, sA1);
    }

    l += __shfl_xor(l, 32, 64);
    const float inv = 1.0f / l;
    #pragma unroll
    for (int r = 0; r < 16; ++r) {
        const int crow = (r & 3) + 8 * (r >> 2) + 4 * hi;
        const float li = __shfl(inv, crow, 64);
        const size_t row = (size_t)b * TT + qt8 * 256 + wave * 32 + crow;
        O[row * DIM + h * 64 + c]      = cvtbf(acc0[r] * li);
        O[row * DIM + h * 64 + 32 + c] = cvtbf(acc1[r] * li);
    }
}

extern "C" void kernel_launch(void* const* d_in, const int* in_sizes, int n_in,
                              void* d_out, int out_size, void* d_ws, size_t ws_size,
                              hipStream_t stream) {
    const float* x  = (const float*)d_in[0];
    // d_in[1] = mask (causal tril; hardcoded in k_attn)
    const float* wq = (const float*)d_in[2];
    const float* wk = (const float*)d_in[3];
    const float* wv = (const float*)d_in[4];
    const float* wo = (const float*)d_in[5];
    const float* ct = (const float*)d_in[6];
    const float* st = (const float*)d_in[7];
    char* ws = (char*)d_ws;
    u16* xb   = (u16*)(ws);
    u16* wqkv = (u16*)(ws + 16777216);
    u16* wob  = (u16*)(ws + 29360128);
    u16* qkv  = (u16*)(ws + 37748736);
    u16* kr   = (u16*)(ws + 62914560);
    u16* vp   = (u16*)(ws + 67108864);
    u16* qr   = xb;                    // reuse after GEMM1
    u16* ao   = qkv;                   // reuse after rope
    u16* vt   = wqkv;                  // reuse after GEMM1

    k_convert_all<<<18432, 256, 0, stream>>>(x, wq, wk, wv, wo, xb, wqkv, wob);

    k_gemm256<3, false><<<(MT / 256) * (3072 / 192), 512, 0, stream>>>(xb, wqkv, qkv, MT, 3072, DIM);
    k_rope<<<MT * 384 / 256, 256, 0, stream>>>(qkv, ct, st, qr, kr, vp);
    k_vtrans<<<BB * NKV * (TT / 64), 256, 0, stream>>>(vp, vt);
    k_attn<<<8 * 64, 512, 0, stream>>>(qr, kr, vt, ao);
    k_gemm256<2, true><<<(MT / 256) * (DIM / 128), 512, 0, stream>>>(ao, wob, d_out, MT, DIM, DIM);
}

// Round 13
// 178.326 us; speedup vs baseline: 1.8564x; 1.8564x over previous
//
#include <hip/hip_runtime.h>
#include <hip/hip_bf16.h>

typedef unsigned short u16;
typedef __attribute__((ext_vector_type(8))) short s16x8;
typedef __attribute__((ext_vector_type(4))) float f32x4;
typedef __attribute__((ext_vector_type(16))) float f32x16;
typedef __attribute__((ext_vector_type(4))) float f32x4v;
typedef __attribute__((ext_vector_type(4))) u16 u16x4;

#define DIM 2048
#define NH 32
#define NKV 8
#define HD 64
#define TT 2048
#define BB 2
#define MT (BB * TT)

__device__ __forceinline__ u16 f2bf(float f) {
    union { float f; unsigned u; } v; v.f = f;
    unsigned r = v.u + 0x7FFFu + ((v.u >> 16) & 1u);
    return (u16)(r >> 16);
}
__device__ __forceinline__ float bf2f(u16 h) {
    union { unsigned u; float f; } v; v.u = ((unsigned)h) << 16;
    return v.f;
}
__device__ __forceinline__ u16 cvtbf(float f) {
    __hip_bfloat16 hb = __float2bfloat16(f);
    return *reinterpret_cast<u16*>(&hb);
}
__device__ __forceinline__ void plane32swap(unsigned& a, unsigned& b) {
#if defined(__has_builtin)
#if __has_builtin(__builtin_amdgcn_permlane32_swap)
    auto t = __builtin_amdgcn_permlane32_swap((int)a, (int)b, false, false);
    a = (unsigned)t[0]; b = (unsigned)t[1];
#else
    asm volatile("v_permlane32_swap_b32 %0, %1" : "+v"(a), "+v"(b));
#endif
#else
    asm volatile("v_permlane32_swap_b32 %0, %1" : "+v"(a), "+v"(b));
#endif
}

// ---------------- fused f32 -> bf16 conversion for all 5 tensors ----------------
__global__ void k_convert_all(const float* __restrict__ x, const float* __restrict__ wq,
                              const float* __restrict__ wk, const float* __restrict__ wv,
                              const float* __restrict__ wo,
                              u16* __restrict__ xb, u16* __restrict__ wqkv, u16* __restrict__ wob) {
    long i = (long)(blockIdx.x * 256 + threadIdx.x) * 4;
    const float* src; u16* dst; long o = i;
    if (o < 8388608L)            { src = x;  dst = xb; }
    else if ((o -= 8388608L) < 4194304L) { src = wq; dst = wqkv; }
    else if ((o -= 4194304L) < 1048576L) { src = wk; dst = wqkv + 4194304L; }
    else if ((o -= 1048576L) < 1048576L) { src = wv; dst = wqkv + 5242880L; }
    else { o -= 1048576L;          src = wo; dst = wob; }
    f32x4v f = *(const f32x4v*)(src + o);
    u16x4 out;
    #pragma unroll
    for (int e = 0; e < 4; ++e) out[e] = f2bf(f[e]);
    *(u16x4*)(dst + o) = out;
}

// ---------------- 256 x (64*BNF) 8-phase bf16 GEMM: C = A @ B^T ----------------
// MODE 0: bf16 C.  MODE 1: fused RoPE+scatter epilogue (GEMM1: writes qo/ko/vo,
// q pre-scaled by (1/8)*log2e; rope pair = adjacent lanes via shfl_xor(1)).
// MODE 2: f32 C (GEMM2).
template<int BNF, int MODE>
__global__ __launch_bounds__(512, 2) void k_gemm256(const u16* __restrict__ A, const u16* __restrict__ B,
                                                    void* __restrict__ C, int M, int N, int K,
                                                    const float* __restrict__ ct, const float* __restrict__ st,
                                                    u16* __restrict__ qo, u16* __restrict__ ko,
                                                    u16* __restrict__ vo) {
    constexpr int BN = 64 * BNF;
    constexpr int BH = 2048 * BNF;               // B half-tile size in u16
    __shared__ u16 LDS[32768 + 4 * BH];
    const int nTn = N / BN;
    const int nwg = gridDim.x;
    const int wg = (blockIdx.x & 7) * (nwg >> 3) + (blockIdx.x >> 3);
    const int tm = wg / nTn, tn = wg % nTn;
    const int tid = threadIdx.x, wid = tid >> 6, lane = tid & 63;
    const int wr = wid >> 2, wc = wid & 3;
    const u16* Ab = A + (size_t)tm * 256 * K;
    const u16* Bb = B + (size_t)tn * BN * K;

    f32x4 acc[8][BNF] = {};
    s16x8 af[4], bfr[BNF];

    auto STAGE_A = [&](int buf, int kk, int kt) {
        u16* base = LDS + (buf * 2 + kk) * 8192;
        const u16* g = Ab + kt * 64 + kk * 32;
        #pragma unroll
        for (int i = 0; i < 2; ++i) {
            const int s = i * 512 + tid;
            const int row = s >> 2;
            const int cl = (s & 3) ^ ((row >> 1) & 3);
            __builtin_amdgcn_global_load_lds(
                (const __attribute__((address_space(1))) void*)(g + (size_t)row * K + cl * 8),
                (__attribute__((address_space(3))) void*)(base + (i * 512 + wid * 64) * 8), 16, 0, 0);
        }
    };
    auto STAGE_B = [&](int buf, int kk, int kt) {
        u16* base = LDS + 32768 + (buf * 2 + kk) * BH;
        const u16* g = Bb + kt * 64 + kk * 32;
        auto one = [&](int ch) {
            const int row = ch * 16 + (lane >> 2);
            const int cl = (lane & 3) ^ ((row >> 1) & 3);
            __builtin_amdgcn_global_load_lds(
                (const __attribute__((address_space(1))) void*)(g + (size_t)row * K + cl * 8),
                (__attribute__((address_space(3))) void*)(base + ch * 512), 16, 0, 0);
        };
        if constexpr (BNF == 4) { one(wid); one(8 + wid); }
        else if constexpr (BNF == 3) { one(wid); one(8 + (wid & 3)); }   // waves 4-7 duplicate
        else { one(wid); }
    };
    auto LDA = [&](int buf, int kk, int mh) {
        const u16* base = LDS + (buf * 2 + kk) * 8192;
        #pragma unroll
        for (int m2 = 0; m2 < 4; ++m2) {
            const int row = wr * 128 + (mh * 4 + m2) * 16 + (lane & 15);
            const int cl = (lane >> 4) ^ ((row >> 1) & 3);
            af[m2] = *(const s16x8*)(base + row * 32 + cl * 8);
        }
    };
    auto LDB = [&](int buf, int kk) {
        const u16* base = LDS + 32768 + (buf * 2 + kk) * BH;
        #pragma unroll
        for (int n = 0; n < BNF; ++n) {
            const int row = wc * (16 * BNF) + n * 16 + (lane & 15);
            const int cl = (lane >> 4) ^ ((row >> 1) & 3);
            bfr[n] = *(const s16x8*)(base + row * 32 + cl * 8);
        }
    };
    auto MFMA16 = [&](int mh) {
        asm volatile("s_waitcnt lgkmcnt(0)" ::: "memory");
        __builtin_amdgcn_sched_barrier(0);
        __builtin_amdgcn_s_setprio(1);
        #pragma unroll
        for (int m2 = 0; m2 < 4; ++m2)
            #pragma unroll
            for (int n = 0; n < BNF; ++n)
                acc[mh * 4 + m2][n] =
                    __builtin_amdgcn_mfma_f32_16x16x32_bf16(af[m2], bfr[n], acc[mh * 4 + m2][n], 0, 0, 0);
        __builtin_amdgcn_s_setprio(0);
    };

    #define VMID() do { if constexpr (BNF == 2) asm volatile("s_waitcnt vmcnt(6)" ::: "memory"); \
                        else                    asm volatile("s_waitcnt vmcnt(8)" ::: "memory"); } while (0)
    #define VONE() do { if constexpr (BNF == 2) asm volatile("s_waitcnt vmcnt(3)" ::: "memory"); \
                        else                    asm volatile("s_waitcnt vmcnt(4)" ::: "memory"); } while (0)

    STAGE_A(0, 0, 0); STAGE_B(0, 0, 0);
    STAGE_A(0, 1, 0); STAGE_B(0, 1, 0);
    STAGE_A(1, 0, 1); STAGE_B(1, 0, 1);
    VMID();
    __builtin_amdgcn_s_barrier();

    const int NI = K >> 7;
    for (int it = 0; it < NI; ++it) {
        const bool last = (it == NI - 1);
        const int t1 = 2 * it + 1;
        LDA(0, 0, 0); LDB(0, 0);
        STAGE_A(1, 1, t1);
        __builtin_amdgcn_s_barrier();
        MFMA16(0);
        __builtin_amdgcn_s_barrier();

        LDA(0, 0, 1);
        STAGE_B(1, 1, t1);
        __builtin_amdgcn_s_barrier();
        MFMA16(1);
        VMID();
        __builtin_amdgcn_s_barrier();

        LDA(0, 1, 0); LDB(0, 1);
        if (!last) STAGE_A(0, 0, t1 + 1);
        __builtin_amdgcn_s_barrier();
        MFMA16(0);
        __builtin_amdgcn_s_barrier();

        LDA(0, 1, 1);
        if (!last) STAGE_B(0, 0, t1 + 1);
        __builtin_amdgcn_s_barrier();
        MFMA16(1);
        if (!last) VMID(); else VONE();
        __builtin_amdgcn_s_barrier();

        LDA(1, 0, 0); LDB(1, 0);
        if (!last) STAGE_A(0, 1, t1 + 1);
        __builtin_amdgcn_s_barrier();
        MFMA16(0);
        __builtin_amdgcn_s_barrier();

        LDA(1, 0, 1);
        if (!last) STAGE_B(0, 1, t1 + 1);
        __builtin_amdgcn_s_barrier();
        MFMA16(1);
        if (!last) VMID(); else asm volatile("s_waitcnt vmcnt(0)" ::: "memory");
        __builtin_amdgcn_s_barrier();

        LDA(1, 1, 0); LDB(1, 1);
        if (!last) STAGE_A(1, 0, t1 + 2);
        __builtin_amdgcn_s_barrier();
        MFMA16(0);
        __builtin_amdgcn_s_barrier();

        LDA(1, 1, 1);
        if (!last) STAGE_B(1, 0, t1 + 2);
        __builtin_amdgcn_s_barrier();
        MFMA16(1);
        if (!last) VMID();
        __builtin_amdgcn_s_barrier();
    }
    #undef VMID
    #undef VONE

    if constexpr (MODE == 1) {
        // fused RoPE + head-scatter: q cols [0,2048) scaled+roped -> qo; k cols
        // [2048,2560) roped -> ko; v cols [2560,3072) passthrough -> vo.
        const float SC2 = 0.18033688f;   // (1/8) * log2(e)
        #pragma unroll
        for (int mf = 0; mf < 8; ++mf)
            #pragma unroll
            for (int n = 0; n < BNF; ++n) {
                const int col = tn * BN + wc * (16 * BNF) + n * 16 + (lane & 15);
                const int d = col & 63;
                #pragma unroll
                for (int r = 0; r < 4; ++r) {
                    const int row = tm * 256 + wr * 128 + mf * 16 + (lane >> 4) * 4 + r;
                    const int bb = row >> 11, t = row & 2047;
                    const float val = acc[mf][n][r];
                    const float p = __shfl_xor(val, 1, 64);   // rope partner (col^1), all lanes
                    if (col < 2560) {
                        const float cc = ct[t * 32 + (d >> 1)];
                        const float ss = st[t * 32 + (d >> 1)];
                        float out = (col & 1) ? (p * ss + val * cc) : (val * cc - p * ss);
                        if (col < 2048) {
                            out *= SC2;
                            qo[((size_t)(bb * NH + (col >> 6)) * TT + t) * HD + d] = f2bf(out);
                        } else {
                            ko[((size_t)(bb * NKV + ((col - 2048) >> 6)) * TT + t) * HD + d] = f2bf(out);
                        }
                    } else {
                        vo[((size_t)(bb * NKV + ((col - 2560) >> 6)) * TT + t) * HD + d] = f2bf(val);
                    }
                }
            }
    } else {
        #pragma unroll
        for (int mf = 0; mf < 8; ++mf)
            #pragma unroll
            for (int n = 0; n < BNF; ++n)
                #pragma unroll
                for (int r = 0; r < 4; ++r) {
                    const int row = tm * 256 + wr * 128 + mf * 16 + (lane >> 4) * 4 + r;
                    const int col = tn * BN + wc * (16 * BNF) + n * 16 + (lane & 15);
                    if (MODE == 2) ((float*)C)[(size_t)row * N + col] = acc[mf][n][r];
                    else           ((u16*)C)[(size_t)row * N + col] = f2bf(acc[mf][n][r]);
                }
    }
}

// ---------------- V transpose: vp [bg][t][d] -> vt [bg][d][t] ----------------
__global__ __launch_bounds__(256) void k_vtrans(const u16* __restrict__ vp, u16* __restrict__ vt) {
    __shared__ u16 tile[64][66];
    const int bg = blockIdx.x >> 5;
    const int t0 = (blockIdx.x & 31) * 64;
    const int tid = threadIdx.x;
    #pragma unroll
    for (int c = 0; c < 2; ++c) {
        const int idx = c * 256 + tid;
        const int tl = idx >> 3, dc = idx & 7;
        s16x8 v = *(const s16x8*)(vp + ((size_t)bg * TT + t0 + tl) * HD + dc * 8);
        *(s16x8*)(&tile[tl][dc * 8]) = v;
    }
    __syncthreads();
    #pragma unroll
    for (int c = 0; c < 2; ++c) {
        const int idx = c * 256 + tid;
        const int d = idx >> 3, tc = idx & 7;
        s16x8 v;
        #pragma unroll
        for (int e = 0; e < 8; ++e) v[e] = (short)tile[tc * 8 + e][d];
        *(s16x8*)(vt + ((size_t)bg * HD + d) * TT + t0 + tc * 8) = v;
    }
}

// ---------------- 8-wave QBLK=256 causal GQA flash attention (proven R9 variant) ----------------
// 512 thr = 8 waves x 32 q-rows. Double-buffered K/V (32 KiB LDS), single barrier per
// 64-kv tile: vmcnt(0) -> barrier -> stage(j+1) -> compute(j). 512 blocks; qt8 mapping
// pairs big+small per CU. Swapped QK^T, in-register P via cvt_pk + permlane32_swap.
__global__ __launch_bounds__(512) void k_attn(const u16* __restrict__ Q, const u16* __restrict__ K,
                                              const u16* __restrict__ Vtg, u16* __restrict__ O) {
    const int bid = blockIdx.x;                 // 512 = 8 qgroups x 64 bh
    const int gq = bid >> 6;
    const int qt8 = (gq < 4) ? (7 - gq) : (gq - 4);   // {7,6,5,4,0,1,2,3}: big first, pair-balanced
    const int bh = bid & 63;
    const int h = bh & 31;
    const int b = bh >> 5;
    const int g = h >> 2;
    __shared__ u16 Ks[2][4096];
    __shared__ u16 Vs[2][4096];                 // V^T tile: [d][kv]
    const int tid = threadIdx.x, wave = tid >> 6, lane = tid & 63;
    const int c = lane & 31, hi = lane >> 5;
    const u16* Qg = Q + ((size_t)(b * NH + h) * TT + qt8 * 256) * HD;
    const u16* Kg = K + (size_t)(b * NKV + g) * TT * HD;
    const u16* Vg = Vtg + (size_t)(b * NKV + g) * HD * TT;

    s16x8 qa[4];
    #pragma unroll
    for (int kb = 0; kb < 4; ++kb)
        qa[kb] = *(const s16x8*)(Qg + (size_t)(wave * 32 + c) * HD + kb * 16 + hi * 8);

    const int rl = lane >> 3, ccl = lane & 7;
    const int sc = ccl ^ rl;                    // chunk-XOR swizzle on source (r&7 == rl)
    auto stage = [&](int jj, int bi) {
        const int r = wave * 8 + rl;            // wave covers rows [wave*8, wave*8+8)
        __builtin_amdgcn_global_load_lds(
            (const __attribute__((address_space(1))) void*)(Kg + ((size_t)(jj * 64 + r)) * HD + sc * 8),
            (__attribute__((address_space(3))) void*)(Ks[bi] + wave * 512), 16, 0, 0);
        __builtin_amdgcn_global_load_lds(
            (const __attribute__((address_space(1))) void*)(Vg + (size_t)r * TT + jj * 64 + sc * 8),
            (__attribute__((address_space(3))) void*)(Vs[bi] + wave * 512), 16, 0, 0);
    };

    f32x16 acc0 = {}, acc1 = {};
    float l = 0.f;
    const int ntiles = 4 * qt8 + 4;

    stage(0, 0);

    for (int j = 0; j < ntiles; ++j) {
        asm volatile("s_waitcnt vmcnt(0)" ::: "memory");   // tile j loads landed
        __builtin_amdgcn_s_barrier();                      // publish buf; prev compute done
        if (j + 1 < ntiles) stage(j + 1, (j + 1) & 1);
        const u16* Kb = Ks[j & 1];
        const u16* Vb = Vs[j & 1];

        f32x16 s0 = {}, s1 = {};
        __builtin_amdgcn_s_setprio(1);
        #pragma unroll
        for (int kb = 0; kb < 4; ++kb) {
            const s16x8 kf0 = *(const s16x8*)(Kb + c * 64 + (((2 * kb + hi) ^ ccl) * 8));
            const s16x8 kf1 = *(const s16x8*)(Kb + (32 + c) * 64 + (((2 * kb + hi) ^ ccl) * 8));
            s0 = __builtin_amdgcn_mfma_f32_32x32x16_bf16(kf0, qa[kb], s0, 0, 0, 0);
            s1 = __builtin_amdgcn_mfma_f32_32x32x16_bf16(kf1, qa[kb], s1, 0, 0, 0);
        }
        __builtin_amdgcn_s_setprio(0);

        if (j >= ntiles - 4) {                  // diagonal 256x256 region
            const int kb64 = (j - (ntiles - 4)) * 64;
            if (kb64 + 63 > wave * 32) {        // wave-uniform: any lane masked?
                const int q_loc = wave * 32 + c;
                #pragma unroll
                for (int r = 0; r < 16; ++r) {
                    const int crow = (r & 3) + 8 * (r >> 2) + 4 * hi;
                    if (kb64 + crow > q_loc)      s0[r] = -1e30f;
                    if (kb64 + 32 + crow > q_loc) s1[r] = -1e30f;
                }
            }
        }
        #pragma unroll
        for (int r = 0; r < 16; ++r) {
            s0[r] = __builtin_amdgcn_exp2f(s0[r]); l += s0[r];
            s1[r] = __builtin_amdgcn_exp2f(s1[r]); l += s1[r];
        }

        unsigned W0[8], W1[8];
        #pragma unroll
        for (int m = 0; m < 8; ++m) {
            float a0f = s0[2 * m], a1f = s0[2 * m + 1];
            float b0f = s1[2 * m], b1f = s1[2 * m + 1];
            asm("v_cvt_pk_bf16_f32 %0, %1, %2" : "=v"(W0[m]) : "v"(a0f), "v"(a1f));
            asm("v_cvt_pk_bf16_f32 %0, %1, %2" : "=v"(W1[m]) : "v"(b0f), "v"(b1f));
        }
        s16x8 pa[4];
        #pragma unroll
        for (int ks = 0; ks < 4; ++ks) {
            const int base = 4 * (ks & 1);
            unsigned a0 = (ks < 2) ? W0[base + 0] : W1[base + 0];
            unsigned b0 = (ks < 2) ? W0[base + 2] : W1[base + 2];
            unsigned a1 = (ks < 2) ? W0[base + 1] : W1[base + 1];
            unsigned b1 = (ks < 2) ? W0[base + 3] : W1[base + 3];
            plane32swap(a0, b0);
            plane32swap(a1, b1);
            union { unsigned w[4]; s16x8 v; } u;
            u.w[0] = a0; u.w[1] = a1; u.w[2] = b0; u.w[3] = b1;
            pa[ks] = u.v;
        }

        __builtin_amdgcn_s_setprio(1);
        #pragma unroll
        for (int kb = 0; kb < 4; ++kb) {
            const s16x8 vb0 = *(const s16x8*)(Vb + c * 64 + (((2 * kb + hi) ^ ccl) * 8));
            const s16x8 vb1 = *(const s16x8*)(Vb + (32 + c) * 64 + (((2 * kb + hi) ^ ccl) * 8));
            acc0 = __builtin_amdgcn_mfma_f32_32x32x16_bf16(pa[kb], vb0, acc0, 0, 0, 0);
            acc1 = __builtin_amdgcn_mfma_f32_32x32x16_bf16(pa[kb], vb1, acc1, 0, 0, 0);
        }
        __builtin_amdgcn_s_setprio(0);
    }

    l += __shfl_xor(l, 32, 64);
    const float inv = 1.0f / l;
    #pragma unroll
    for (int r = 0; r < 16; ++r) {
        const int crow = (r & 3) + 8 * (r >> 2) + 4 * hi;
        const float li = __shfl(inv, crow, 64);
        const size_t row = (size_t)b * TT + qt8 * 256 + wave * 32 + crow;
        O[row * DIM + h * 64 + c]      = cvtbf(acc0[r] * li);
        O[row * DIM + h * 64 + 32 + c] = cvtbf(acc1[r] * li);
    }
}

extern "C" void kernel_launch(void* const* d_in, const int* in_sizes, int n_in,
                              void* d_out, int out_size, void* d_ws, size_t ws_size,
                              hipStream_t stream) {
    const float* x  = (const float*)d_in[0];
    // d_in[1] = mask (causal tril; hardcoded in k_attn)
    const float* wq = (const float*)d_in[2];
    const float* wk = (const float*)d_in[3];
    const float* wv = (const float*)d_in[4];
    const float* wo = (const float*)d_in[5];
    const float* ct = (const float*)d_in[6];
    const float* st = (const float*)d_in[7];
    char* ws = (char*)d_ws;
    u16* xb   = (u16*)(ws);
    u16* wqkv = (u16*)(ws + 16777216);
    u16* wob  = (u16*)(ws + 29360128);
    u16* ao   = (u16*)(ws + 37748736);
    u16* kr   = (u16*)(ws + 62914560);
    u16* vp   = (u16*)(ws + 67108864);
    u16* qr   = xb;                    // reuse after GEMM1 (epilogue writes qr; A=xb read done)
    u16* vt   = wqkv;                  // reuse after GEMM1

    k_convert_all<<<18432, 256, 0, stream>>>(x, wq, wk, wv, wo, xb, wqkv, wob);

    // GEMM1 with fused RoPE+scatter epilogue (writes qr/kr/vp directly; no qkv buffer)
    k_gemm256<3, 1><<<(MT / 256) * (3072 / 192), 512, 0, stream>>>(
        xb, wqkv, nullptr, MT, 3072, DIM, ct, st, qr, kr, vp);
    k_vtrans<<<BB * NKV * (TT / 64), 256, 0, stream>>>(vp, vt);
    k_attn<<<8 * 64, 512, 0, stream>>>(qr, kr, vt, ao);
    k_gemm256<2, 2><<<(MT / 256) * (DIM / 128), 512, 0, stream>>>(
        ao, wob, d_out, MT, DIM, DIM, nullptr, nullptr, nullptr, nullptr, nullptr);
}

// Round 14
// 168.681 us; speedup vs baseline: 1.9625x; 1.0572x over previous
//
#include <hip/hip_runtime.h>
#include <hip/hip_bf16.h>

typedef unsigned short u16;
typedef __attribute__((ext_vector_type(8))) short s16x8;
typedef __attribute__((ext_vector_type(4))) float f32x4;
typedef __attribute__((ext_vector_type(16))) float f32x16;
typedef __attribute__((ext_vector_type(4))) float f32x4v;
typedef __attribute__((ext_vector_type(4))) u16 u16x4;

#define DIM 2048
#define NH 32
#define NKV 8
#define HD 64
#define TT 2048
#define BB 2
#define MT (BB * TT)

__device__ __forceinline__ u16 f2bf(float f) {
    union { float f; unsigned u; } v; v.f = f;
    unsigned r = v.u + 0x7FFFu + ((v.u >> 16) & 1u);
    return (u16)(r >> 16);
}
__device__ __forceinline__ float bf2f(u16 h) {
    union { unsigned u; float f; } v; v.u = ((unsigned)h) << 16;
    return v.f;
}
__device__ __forceinline__ u16 cvtbf(float f) {
    __hip_bfloat16 hb = __float2bfloat16(f);
    return *reinterpret_cast<u16*>(&hb);
}
__device__ __forceinline__ void plane32swap(unsigned& a, unsigned& b) {
#if defined(__has_builtin)
#if __has_builtin(__builtin_amdgcn_permlane32_swap)
    auto t = __builtin_amdgcn_permlane32_swap((int)a, (int)b, false, false);
    a = (unsigned)t[0]; b = (unsigned)t[1];
#else
    asm volatile("v_permlane32_swap_b32 %0, %1" : "+v"(a), "+v"(b));
#endif
#else
    asm volatile("v_permlane32_swap_b32 %0, %1" : "+v"(a), "+v"(b));
#endif
}

// ---------------- fused f32 -> bf16 conversion for all 5 tensors ----------------
__global__ void k_convert_all(const float* __restrict__ x, const float* __restrict__ wq,
                              const float* __restrict__ wk, const float* __restrict__ wv,
                              const float* __restrict__ wo,
                              u16* __restrict__ xb, u16* __restrict__ wqkv, u16* __restrict__ wob) {
    long i = (long)(blockIdx.x * 256 + threadIdx.x) * 4;
    const float* src; u16* dst; long o = i;
    if (o < 8388608L)            { src = x;  dst = xb; }
    else if ((o -= 8388608L) < 4194304L) { src = wq; dst = wqkv; }
    else if ((o -= 4194304L) < 1048576L) { src = wk; dst = wqkv + 4194304L; }
    else if ((o -= 1048576L) < 1048576L) { src = wv; dst = wqkv + 5242880L; }
    else { o -= 1048576L;          src = wo; dst = wob; }
    f32x4v f = *(const f32x4v*)(src + o);
    u16x4 out;
    #pragma unroll
    for (int e = 0; e < 4; ++e) out[e] = f2bf(f[e]);
    *(u16x4*)(dst + o) = out;
}

// ---------------- 256 x (64*BNF) 8-phase bf16 GEMM: C = A @ B^T ----------------
template<int BNF, bool OUTF32>
__global__ __launch_bounds__(512, 2) void k_gemm256(const u16* __restrict__ A, const u16* __restrict__ B,
                                                    void* __restrict__ C, int M, int N, int K) {
    constexpr int BN = 64 * BNF;
    constexpr int BH = 2048 * BNF;               // B half-tile size in u16
    __shared__ u16 LDS[32768 + 4 * BH];
    const int nTn = N / BN;
    const int nwg = gridDim.x;
    const int wg = (blockIdx.x & 7) * (nwg >> 3) + (blockIdx.x >> 3);
    const int tm = wg / nTn, tn = wg % nTn;
    const int tid = threadIdx.x, wid = tid >> 6, lane = tid & 63;
    const int wr = wid >> 2, wc = wid & 3;
    const u16* Ab = A + (size_t)tm * 256 * K;
    const u16* Bb = B + (size_t)tn * BN * K;

    f32x4 acc[8][BNF] = {};
    s16x8 af[4], bfr[BNF];

    auto STAGE_A = [&](int buf, int kk, int kt) {
        u16* base = LDS + (buf * 2 + kk) * 8192;
        const u16* g = Ab + kt * 64 + kk * 32;
        #pragma unroll
        for (int i = 0; i < 2; ++i) {
            const int s = i * 512 + tid;
            const int row = s >> 2;
            const int cl = (s & 3) ^ ((row >> 1) & 3);
            __builtin_amdgcn_global_load_lds(
                (const __attribute__((address_space(1))) void*)(g + (size_t)row * K + cl * 8),
                (__attribute__((address_space(3))) void*)(base + (i * 512 + wid * 64) * 8), 16, 0, 0);
        }
    };
    auto STAGE_B = [&](int buf, int kk, int kt) {
        u16* base = LDS + 32768 + (buf * 2 + kk) * BH;
        const u16* g = Bb + kt * 64 + kk * 32;
        auto one = [&](int ch) {
            const int row = ch * 16 + (lane >> 2);
            const int cl = (lane & 3) ^ ((row >> 1) & 3);
            __builtin_amdgcn_global_load_lds(
                (const __attribute__((address_space(1))) void*)(g + (size_t)row * K + cl * 8),
                (__attribute__((address_space(3))) void*)(base + ch * 512), 16, 0, 0);
        };
        if constexpr (BNF == 4) { one(wid); one(8 + wid); }
        else if constexpr (BNF == 3) { one(wid); one(8 + (wid & 3)); }   // waves 4-7 duplicate
        else { one(wid); }
    };
    auto LDA = [&](int buf, int kk, int mh) {
        const u16* base = LDS + (buf * 2 + kk) * 8192;
        #pragma unroll
        for (int m2 = 0; m2 < 4; ++m2) {
            const int row = wr * 128 + (mh * 4 + m2) * 16 + (lane & 15);
            const int cl = (lane >> 4) ^ ((row >> 1) & 3);
            af[m2] = *(const s16x8*)(base + row * 32 + cl * 8);
        }
    };
    auto LDB = [&](int buf, int kk) {
        const u16* base = LDS + 32768 + (buf * 2 + kk) * BH;
        #pragma unroll
        for (int n = 0; n < BNF; ++n) {
            const int row = wc * (16 * BNF) + n * 16 + (lane & 15);
            const int cl = (lane >> 4) ^ ((row >> 1) & 3);
            bfr[n] = *(const s16x8*)(base + row * 32 + cl * 8);
        }
    };
    auto MFMA16 = [&](int mh) {
        asm volatile("s_waitcnt lgkmcnt(0)" ::: "memory");
        __builtin_amdgcn_sched_barrier(0);
        __builtin_amdgcn_s_setprio(1);
        #pragma unroll
        for (int m2 = 0; m2 < 4; ++m2)
            #pragma unroll
            for (int n = 0; n < BNF; ++n)
                acc[mh * 4 + m2][n] =
                    __builtin_amdgcn_mfma_f32_16x16x32_bf16(af[m2], bfr[n], acc[mh * 4 + m2][n], 0, 0, 0);
        __builtin_amdgcn_s_setprio(0);
    };

    #define VMID() do { if constexpr (BNF == 2) asm volatile("s_waitcnt vmcnt(6)" ::: "memory"); \
                        else                    asm volatile("s_waitcnt vmcnt(8)" ::: "memory"); } while (0)
    #define VONE() do { if constexpr (BNF == 2) asm volatile("s_waitcnt vmcnt(3)" ::: "memory"); \
                        else                    asm volatile("s_waitcnt vmcnt(4)" ::: "memory"); } while (0)

    STAGE_A(0, 0, 0); STAGE_B(0, 0, 0);
    STAGE_A(0, 1, 0); STAGE_B(0, 1, 0);
    STAGE_A(1, 0, 1); STAGE_B(1, 0, 1);
    VMID();
    __builtin_amdgcn_s_barrier();

    const int NI = K >> 7;
    for (int it = 0; it < NI; ++it) {
        const bool last = (it == NI - 1);
        const int t1 = 2 * it + 1;
        LDA(0, 0, 0); LDB(0, 0);
        STAGE_A(1, 1, t1);
        __builtin_amdgcn_s_barrier();
        MFMA16(0);
        __builtin_amdgcn_s_barrier();

        LDA(0, 0, 1);
        STAGE_B(1, 1, t1);
        __builtin_amdgcn_s_barrier();
        MFMA16(1);
        VMID();
        __builtin_amdgcn_s_barrier();

        LDA(0, 1, 0); LDB(0, 1);
        if (!last) STAGE_A(0, 0, t1 + 1);
        __builtin_amdgcn_s_barrier();
        MFMA16(0);
        __builtin_amdgcn_s_barrier();

        LDA(0, 1, 1);
        if (!last) STAGE_B(0, 0, t1 + 1);
        __builtin_amdgcn_s_barrier();
        MFMA16(1);
        if (!last) VMID(); else VONE();
        __builtin_amdgcn_s_barrier();

        LDA(1, 0, 0); LDB(1, 0);
        if (!last) STAGE_A(0, 1, t1 + 1);
        __builtin_amdgcn_s_barrier();
        MFMA16(0);
        __builtin_amdgcn_s_barrier();

        LDA(1, 0, 1);
        if (!last) STAGE_B(0, 1, t1 + 1);
        __builtin_amdgcn_s_barrier();
        MFMA16(1);
        if (!last) VMID(); else asm volatile("s_waitcnt vmcnt(0)" ::: "memory");
        __builtin_amdgcn_s_barrier();

        LDA(1, 1, 0); LDB(1, 1);
        if (!last) STAGE_A(1, 0, t1 + 2);
        __builtin_amdgcn_s_barrier();
        MFMA16(0);
        __builtin_amdgcn_s_barrier();

        LDA(1, 1, 1);
        if (!last) STAGE_B(1, 0, t1 + 2);
        __builtin_amdgcn_s_barrier();
        MFMA16(1);
        if (!last) VMID();
        __builtin_amdgcn_s_barrier();
    }
    #undef VMID
    #undef VONE

    #pragma unroll
    for (int mf = 0; mf < 8; ++mf)
        #pragma unroll
        for (int n = 0; n < BNF; ++n)
            #pragma unroll
            for (int r = 0; r < 4; ++r) {
                const int row = tm * 256 + wr * 128 + mf * 16 + (lane >> 4) * 4 + r;
                const int col = tn * BN + wc * (16 * BNF) + n * 16 + (lane & 15);
                if (OUTF32) ((float*)C)[(size_t)row * N + col] = acc[mf][n][r];
                else        ((u16*)C)[(size_t)row * N + col] = f2bf(acc[mf][n][r]);
            }
}

// ---------------- RoPE + scatter (q,k only), vectorized; q pre-scaled by (1/8)*log2(e) ----------------
__global__ void k_rope(const u16* __restrict__ qkv, const float* __restrict__ ct, const float* __restrict__ st,
                       u16* __restrict__ qo, u16* __restrict__ ko) {
    const int idx = blockIdx.x * 256 + threadIdx.x;   // MT * 320 chunks of 8 u16 (q+k cols only)
    const int c = idx % 320;
    const int bt = idx / 320;
    const int b = bt / TT, t = bt % TT;
    const s16x8 v = *(const s16x8*)(qkv + (size_t)bt * 3072 + c * 8);
    const bool isq = c < 256;
    const int base = isq ? c : c - 256;
    const int hh = base >> 3;
    const int di0 = (base & 7) * 4;
    const f32x4v cc = *(const f32x4v*)(ct + t * 32 + di0);
    const f32x4v ss = *(const f32x4v*)(st + t * 32 + di0);
    const float QS = isq ? 0.18033688f : 1.0f;
    s16x8 o;
    #pragma unroll
    for (int p = 0; p < 4; ++p) {
        const float x0 = bf2f((u16)v[2 * p]), x1 = bf2f((u16)v[2 * p + 1]);
        o[2 * p]     = (short)cvtbf((x0 * cc[p] - x1 * ss[p]) * QS);
        o[2 * p + 1] = (short)cvtbf((x0 * ss[p] + x1 * cc[p]) * QS);
    }
    u16* dst = isq ? (qo + ((size_t)(b * NH + hh) * TT + t) * HD + 2 * di0)
                   : (ko + ((size_t)(b * NKV + hh) * TT + t) * HD + 2 * di0);
    *(s16x8*)dst = o;
}

// ---------------- V transpose straight from qkv: cols [2560,3072) -> vt [bg][d][t] ----------------
__global__ __launch_bounds__(256) void k_vtrans(const u16* __restrict__ qkv, u16* __restrict__ vt) {
    __shared__ u16 tile[64][66];
    const int bg = blockIdx.x >> 5;
    const int b = bg >> 3, g = bg & 7;
    const int t0 = (blockIdx.x & 31) * 64;
    const int tid = threadIdx.x;
    #pragma unroll
    for (int c = 0; c < 2; ++c) {
        const int idx = c * 256 + tid;
        const int tl = idx >> 3, dc = idx & 7;
        s16x8 v = *(const s16x8*)(qkv + ((size_t)(b * TT + t0 + tl)) * 3072 + 2560 + g * 64 + dc * 8);
        *(s16x8*)(&tile[tl][dc * 8]) = v;
    }
    __syncthreads();
    #pragma unroll
    for (int c = 0; c < 2; ++c) {
        const int idx = c * 256 + tid;
        const int d = idx >> 3, tc = idx & 7;
        s16x8 v;
        #pragma unroll
        for (int e = 0; e < 8; ++e) v[e] = (short)tile[tc * 8 + e][d];
        *(s16x8*)(vt + ((size_t)bg * HD + d) * TT + t0 + tc * 8) = v;
    }
}

// ---------------- 8-wave QBLK=256 causal GQA flash attention (R9 structure) ----------------
// Double-buffered K/V, single barrier per tile: vmcnt(0) -> barrier -> stage(j+1) -> compute(j).
// NEW: bank-rotation swizzle includes row>>3 (sc ^= wave at stage; slot ^= c>>3 at read) so
// rows c, c+8, c+16, c+24 hit distinct 16B slots -> distinct banks on every fragment read.
__global__ __launch_bounds__(512) void k_attn(const u16* __restrict__ Q, const u16* __restrict__ K,
                                              const u16* __restrict__ Vtg, u16* __restrict__ O) {
    const int bid = blockIdx.x;                 // 512 = 8 qgroups x 64 bh
    const int gq = bid >> 6;
    const int qt8 = (gq < 4) ? (7 - gq) : (gq - 4);   // big first, pair-balanced
    const int bh = bid & 63;
    const int h = bh & 31;
    const int b = bh >> 5;
    const int g = h >> 2;
    __shared__ u16 Ks[2][4096];
    __shared__ u16 Vs[2][4096];                 // V^T tile: [d][kv]
    const int tid = threadIdx.x, wave = tid >> 6, lane = tid & 63;
    const int c = lane & 31, hi = lane >> 5;
    const u16* Qg = Q + ((size_t)(b * NH + h) * TT + qt8 * 256) * HD;
    const u16* Kg = K + (size_t)(b * NKV + g) * TT * HD;
    const u16* Vg = Vtg + (size_t)(b * NKV + g) * HD * TT;

    s16x8 qa[4];
    #pragma unroll
    for (int kb = 0; kb < 4; ++kb)
        qa[kb] = *(const s16x8*)(Qg + (size_t)(wave * 32 + c) * HD + kb * 16 + hi * 8);

    const int rl = lane >> 3, ccl = lane & 7;
    const int sc = ccl ^ rl ^ wave;             // chunk swizzle incl. row>>3 (= wave)
    const int rsh = c >> 3;                     // row>>3 for read rows 0..31; +4 for 32..63
    auto stage = [&](int jj, int bi) {
        const int r = wave * 8 + rl;            // wave covers rows [wave*8, wave*8+8)
        __builtin_amdgcn_global_load_lds(
            (const __attribute__((address_space(1))) void*)(Kg + ((size_t)(jj * 64 + r)) * HD + sc * 8),
            (__attribute__((address_space(3))) void*)(Ks[bi] + wave * 512), 16, 0, 0);
        __builtin_amdgcn_global_load_lds(
            (const __attribute__((address_space(1))) void*)(Vg + (size_t)r * TT + jj * 64 + sc * 8),
            (__attribute__((address_space(3))) void*)(Vs[bi] + wave * 512), 16, 0, 0);
    };

    f32x16 acc0 = {}, acc1 = {};
    float l = 0.f;
    const int ntiles = 4 * qt8 + 4;

    stage(0, 0);

    for (int j = 0; j < ntiles; ++j) {
        asm volatile("s_waitcnt vmcnt(0)" ::: "memory");   // tile j loads landed
        __builtin_amdgcn_s_barrier();                      // publish buf; prev compute done
        if (j + 1 < ntiles) stage(j + 1, (j + 1) & 1);
        const u16* Kb = Ks[j & 1];
        const u16* Vb = Vs[j & 1];

        f32x16 s0 = {}, s1 = {};
        __builtin_amdgcn_s_setprio(1);
        #pragma unroll
        for (int kb = 0; kb < 4; ++kb) {
            const int sl0 = (2 * kb + hi) ^ ccl ^ rsh;
            const s16x8 kf0 = *(const s16x8*)(Kb + c * 64 + sl0 * 8);
            const s16x8 kf1 = *(const s16x8*)(Kb + (32 + c) * 64 + (sl0 ^ 4) * 8);
            s0 = __builtin_amdgcn_mfma_f32_32x32x16_bf16(kf0, qa[kb], s0, 0, 0, 0);
            s1 = __builtin_amdgcn_mfma_f32_32x32x16_bf16(kf1, qa[kb], s1, 0, 0, 0);
        }
        __builtin_amdgcn_s_setprio(0);

        if (j >= ntiles - 4) {                  // diagonal 256x256 region
            const int kb64 = (j - (ntiles - 4)) * 64;
            if (kb64 + 63 > wave * 32) {        // wave-uniform: any lane masked?
                const int q_loc = wave * 32 + c;
                #pragma unroll
                for (int r = 0; r < 16; ++r) {
                    const int crow = (r & 3) + 8 * (r >> 2) + 4 * hi;
                    if (kb64 + crow > q_loc)      s0[r] = -1e30f;
                    if (kb64 + 32 + crow > q_loc) s1[r] = -1e30f;
                }
            }
        }
        #pragma unroll
        for (int r = 0; r < 16; ++r) {
            s0[r] = __builtin_amdgcn_exp2f(s0[r]); l += s0[r];
            s1[r] = __builtin_amdgcn_exp2f(s1[r]); l += s1[r];
        }

        unsigned W0[8], W1[8];
        #pragma unroll
        for (int m = 0; m < 8; ++m) {
            float a0f = s0[2 * m], a1f = s0[2 * m + 1];
            float b0f = s1[2 * m], b1f = s1[2 * m + 1];
            asm("v_cvt_pk_bf16_f32 %0, %1, %2" : "=v"(W0[m]) : "v"(a0f), "v"(a1f));
            asm("v_cvt_pk_bf16_f32 %0, %1, %2" : "=v"(W1[m]) : "v"(b0f), "v"(b1f));
        }
        s16x8 pa[4];
        #pragma unroll
        for (int ks = 0; ks < 4; ++ks) {
            const int base = 4 * (ks & 1);
            unsigned a0 = (ks < 2) ? W0[base + 0] : W1[base + 0];
            unsigned b0 = (ks < 2) ? W0[base + 2] : W1[base + 2];
            unsigned a1 = (ks < 2) ? W0[base + 1] : W1[base + 1];
            unsigned b1 = (ks < 2) ? W0[base + 3] : W1[base + 3];
            plane32swap(a0, b0);
            plane32swap(a1, b1);
            union { unsigned w[4]; s16x8 v; } u;
            u.w[0] = a0; u.w[1] = a1; u.w[2] = b0; u.w[3] = b1;
            pa[ks] = u.v;
        }

        __builtin_amdgcn_s_setprio(1);
        #pragma unroll
        for (int kb = 0; kb < 4; ++kb) {
            const int sl0 = (2 * kb + hi) ^ ccl ^ rsh;
            const s16x8 vb0 = *(const s16x8*)(Vb + c * 64 + sl0 * 8);
            const s16x8 vb1 = *(const s16x8*)(Vb + (32 + c) * 64 + (sl0 ^ 4) * 8);
            acc0 = __builtin_amdgcn_mfma_f32_32x32x16_bf16(pa[kb], vb0, acc0, 0, 0, 0);
            acc1 = __builtin_amdgcn_mfma_f32_32x32x16_bf16(pa[kb], vb1, acc1, 0, 0, 0);
        }
        __builtin_amdgcn_s_setprio(0);
    }

    l += __shfl_xor(l, 32, 64);
    const float inv = 1.0f / l;
    #pragma unroll
    for (int r = 0; r < 16; ++r) {
        const int crow = (r & 3) + 8 * (r >> 2) + 4 * hi;
        const float li = __shfl(inv, crow, 64);
        const size_t row = (size_t)b * TT + qt8 * 256 + wave * 32 + crow;
        O[row * DIM + h * 64 + c]      = cvtbf(acc0[r] * li);
        O[row * DIM + h * 64 + 32 + c] = cvtbf(acc1[r] * li);
    }
}

extern "C" void kernel_launch(void* const* d_in, const int* in_sizes, int n_in,
                              void* d_out, int out_size, void* d_ws, size_t ws_size,
                              hipStream_t stream) {
    const float* x  = (const float*)d_in[0];
    // d_in[1] = mask (causal tril; hardcoded in k_attn)
    const float* wq = (const float*)d_in[2];
    const float* wk = (const float*)d_in[3];
    const float* wv = (const float*)d_in[4];
    const float* wo = (const float*)d_in[5];
    const float* ct = (const float*)d_in[6];
    const float* st = (const float*)d_in[7];
    char* ws = (char*)d_ws;
    u16* xb   = (u16*)(ws);
    u16* wqkv = (u16*)(ws + 16777216);
    u16* wob  = (u16*)(ws + 29360128);
    u16* qkv  = (u16*)(ws + 37748736);
    u16* kr   = (u16*)(ws + 62914560);
    u16* qr   = xb;                    // reuse after GEMM1
    u16* ao   = qkv;                   // reuse after rope+vtrans consumed qkv
    u16* vt   = wqkv;                  // reuse after GEMM1

    k_convert_all<<<18432, 256, 0, stream>>>(x, wq, wk, wv, wo, xb, wqkv, wob);

    k_gemm256<3, false><<<(MT / 256) * (3072 / 192), 512, 0, stream>>>(xb, wqkv, qkv, MT, 3072, DIM);
    k_rope<<<MT * 320 / 256, 256, 0, stream>>>(qkv, ct, st, qr, kr);
    k_vtrans<<<BB * NKV * (TT / 64), 256, 0, stream>>>(qkv, vt);
    k_attn<<<8 * 64, 512, 0, stream>>>(qr, kr, vt, ao);
    k_gemm256<2, true><<<(MT / 256) * (DIM / 128), 512, 0, stream>>>(ao, wob, d_out, MT, DIM, DIM);
}